// Round 2
// baseline (570.354 us; speedup 1.0000x reference)
//
#include <hip/hip_runtime.h>
#include <hip/hip_fp16.h>

#define D 64
#define NKR 16
#define NB 1024
#define NL 8

typedef __attribute__((ext_vector_type(8))) _Float16 half8;
typedef __attribute__((ext_vector_type(16))) float f32x16;
typedef __attribute__((ext_vector_type(4))) int i32x4;

static __device__ __forceinline__ half8 neg8(half8 x) {
    i32x4 u = __builtin_bit_cast(i32x4, x);
    u = u ^ (int)0x80008000;
    return __builtin_bit_cast(half8, u);
}

static __device__ __forceinline__ unsigned pkrtz(float a, float b) {
    auto h = __builtin_amdgcn_cvt_pkrtz(a, b);   // __fp16 ext_vector_type(2)
    return __builtin_bit_cast(unsigned, h);
}

// v_permlane32_swap_b32: a.row1 <-> b.row0 (row = 32-lane half).
// After: a = [a.low | b.low(moved up)], b = [a.high(moved down) | b.high].
static __device__ __forceinline__ void plswap(unsigned &a, unsigned &b) {
    asm volatile("v_permlane32_swap_b32 %0, %1" : "+v"(a), "+v"(b));
}

union Pack4 { _Float16 h[4]; uint2 u; };
union H8 { unsigned u[4]; uint2 v[2]; half8 h; };

#define GLDS16(gp, lp) \
    __builtin_amdgcn_global_load_lds((const __attribute__((address_space(1))) void*)(gp), \
                                     (__attribute__((address_space(3))) void*)(lp), 16, 0, 0)

#define MFMA __builtin_amdgcn_mfma_f32_32x32x16_f16

// kraus fp32 -> fp16, layout [L][K][2][64][64] with XOR-swizzled 8B (4-half) granules:
// element (plane,row,col) -> plane*4096 + row*64 + (((col>>2)^(row&15))<<2) + (col&3)
// 16-way spread -> 2-way bank aliasing on ds_read_b64 (free), vs 4-way at 16B granules.
__global__ void kconv_kernel(const float* __restrict__ re, const float* __restrict__ im,
                             _Float16* __restrict__ out) {
    int plane = blockIdx.y;
    int idx = blockIdx.x * blockDim.x + threadIdx.x;
    const float* src = plane ? im : re;
    float4 v = ((const float4*)src)[idx];
    int e = idx * 4;
    int lk = e >> 12;
    int rem = e & 4095;
    int row = rem >> 6, col = rem & 63;          // col multiple of 4 -> one granule
    int grp = (col >> 2) ^ (row & 15);
    Pack4 p;
    p.h[0] = (_Float16)v.x; p.h[1] = (_Float16)v.y;
    p.h[2] = (_Float16)v.z; p.h[3] = (_Float16)v.w;
    *(uint2*)(out + ((size_t)lk * 2 + plane) * 4096 + row * 64 + grp * 4) = p.u;
}

// state fp32 -> fp16 transposed: out[b][plane][l][j] = state[b][j][l]  (rho^T row-major)
__global__ void sconv_kernel(const float* __restrict__ re, const float* __restrict__ im,
                             _Float16* __restrict__ out) {
    __shared__ float tile[64][65];
    int b = blockIdx.x;
    int t = threadIdx.x;
    for (int plane = 0; plane < 2; ++plane) {
        const float* src = (plane ? im : re) + (size_t)b * 4096;
        __syncthreads();
        #pragma unroll
        for (int i = 0; i < 16; ++i) {
            int e = t + 256 * i;
            tile[e >> 6][e & 63] = src[e];
        }
        __syncthreads();
        _Float16* o = out + ((size_t)b * 2 + plane) * 4096;
        #pragma unroll
        for (int i = 0; i < 16; ++i) {
            int e = t + 256 * i;            // e = l*64 + j
            o[e] = (_Float16)tile[e & 63][e >> 6];
        }
    }
}

// Convert one stage-1 f32x16 accumulator tile (C-layout: lane=col i, reg 4g+j -> row
// l_rel = 8g+4hl+j) into two stage-2 A-fragments (lane=row i, halves at l_rel
// 16s+8hl+0..7) entirely in registers: 8 cvt_pkrtz + 4 permlane32_swap.
static __device__ __forceinline__ void exchange(const f32x16 &dd, half8 &f0, half8 &f1) {
    unsigned A0 = pkrtz(dd[0],  dd[1]),  B0 = pkrtz(dd[2],  dd[3]);
    unsigned A1 = pkrtz(dd[4],  dd[5]),  B1 = pkrtz(dd[6],  dd[7]);
    unsigned A2 = pkrtz(dd[8],  dd[9]),  B2 = pkrtz(dd[10], dd[11]);
    unsigned A3 = pkrtz(dd[12], dd[13]), B3 = pkrtz(dd[14], dd[15]);
    plswap(A0, A1);   // A0 = [own g0 | partner g1] = w0 ; A1 = [partner g0 | own g1] = w2
    plswap(B0, B1);   // w1, w3
    plswap(A2, A3);   // frag1 w0, w2
    plswap(B2, B3);   // frag1 w1, w3
    H8 h0; h0.u[0] = A0; h0.u[1] = B0; h0.u[2] = A1; h0.u[3] = B1; f0 = h0.h;
    H8 h1; h1.u[0] = A2; h1.u[1] = B2; h1.u[2] = A3; h1.u[3] = B3; f1 = h1.h;
}

// One kraus step for a wave with i-tile IT (template so all acc/B indexing is static).
// Stage 1: T^T tiles for rho r=wc, i in [32*IT,32*IT+32), both l-halves (A = rho^T rows,
// B = K rows 32*IT+l31). Stage 2: rho_new rows i, both m-tiles; A-frags come from the
// in-register exchange, B for mt=IT reuses stage-1 fragments, mt=1-IT read fresh.
template<int IT>
static __device__ __forceinline__ void kstep(
    const _Float16* __restrict__ KB,
    const half8 (&a1re)[2][4], const half8 (&a1im)[2][4],
    f32x16 (&accRe)[2], f32x16 (&accIm)[2],
    int l31, int hl)
{
    // ---- B(mt=IT): rows 32*IT + l31; 2x ds_read_b64 per half8 (swizzled granules) ----
    half8 bre0[4], bim0[4];
    {
        const int brow = 32 * IT + l31;
        const int base = brow * 64;
        const int rx = brow & 15;
        #pragma unroll
        for (int ks = 0; ks < 4; ++ks) {
            const int g = 4 * ks + 2 * hl;                 // even
            const int p = ((g ^ rx) << 2);
            const int q = (((g + 1) ^ rx) << 2);
            H8 t;
            t.v[0] = *(const uint2*)&KB[base + p];
            t.v[1] = *(const uint2*)&KB[base + q];
            bre0[ks] = t.h;
            t.v[0] = *(const uint2*)&KB[4096 + base + p];
            t.v[1] = *(const uint2*)&KB[4096 + base + q];
            bim0[ks] = t.h;
        }
    }

    // ---- stage 1: dd[lh] = T^T tile; then register exchange -> A-frags ----
    half8 af_re[4], af_im[4];
    #pragma unroll
    for (int lh = 0; lh < 2; ++lh) {
        f32x16 ddre, ddim;
        #pragma unroll
        for (int i = 0; i < 16; ++i) { ddre[i] = 0.f; ddim[i] = 0.f; }
        #pragma unroll
        for (int ks = 0; ks < 4; ++ks) {
            half8 bn = neg8(bim0[ks]);
            ddre = MFMA(a1re[lh][ks], bre0[ks], ddre, 0, 0, 0);
            ddre = MFMA(a1im[lh][ks], bn,       ddre, 0, 0, 0);
            ddim = MFMA(a1re[lh][ks], bim0[ks], ddim, 0, 0, 0);
            ddim = MFMA(a1im[lh][ks], bre0[ks], ddim, 0, 0, 0);
        }
        exchange(ddre, af_re[2 * lh], af_re[2 * lh + 1]);
        exchange(ddim, af_im[2 * lh], af_im[2 * lh + 1]);
    }

    // ---- stage 2, mt = IT (B reused from stage 1) ----
    #pragma unroll
    for (int ks = 0; ks < 4; ++ks) {
        half8 an = neg8(af_re[ks]);
        accRe[IT] = MFMA(af_re[ks], bre0[ks], accRe[IT], 0, 0, 0);
        accRe[IT] = MFMA(af_im[ks], bim0[ks], accRe[IT], 0, 0, 0);
        accIm[IT] = MFMA(af_im[ks], bre0[ks], accIm[IT], 0, 0, 0);
        accIm[IT] = MFMA(an,        bim0[ks], accIm[IT], 0, 0, 0);
    }

    // ---- stage 2, mt = 1-IT (fresh B, per-ks to bound liveness) ----
    {
        const int brow = 32 * (1 - IT) + l31;
        const int base = brow * 64;
        const int rx = brow & 15;
        #pragma unroll
        for (int ks = 0; ks < 4; ++ks) {
            const int g = 4 * ks + 2 * hl;
            const int p = ((g ^ rx) << 2);
            const int q = (((g + 1) ^ rx) << 2);
            H8 t;
            t.v[0] = *(const uint2*)&KB[base + p];
            t.v[1] = *(const uint2*)&KB[base + q];
            half8 br = t.h;
            t.v[0] = *(const uint2*)&KB[4096 + base + p];
            t.v[1] = *(const uint2*)&KB[4096 + base + q];
            half8 bi = t.h;
            half8 an = neg8(af_re[ks]);
            accRe[1 - IT] = MFMA(af_re[ks], br, accRe[1 - IT], 0, 0, 0);
            accRe[1 - IT] = MFMA(af_im[ks], bi, accRe[1 - IT], 0, 0, 0);
            accIm[1 - IT] = MFMA(af_im[ks], br, accIm[1 - IT], 0, 0, 0);
            accIm[1 - IT] = MFMA(an,        bi, accIm[1 - IT], 0, 0, 0);
        }
    }
}

// One block per 2 rho; wave (wr,wc): rho r=wc, output i-tile wr, all m. No T round-trip
// through LDS (permlane exchange instead); K double-buffered in LDS, 1 barrier/kraus.
__global__ __launch_bounds__(256, 2) void layer_kernel(
    const _Float16* __restrict__ rho_in,
    _Float16* __restrict__ rho_out,
    float* __restrict__ final_out,
    const _Float16* __restrict__ kraus,   // this layer, swizzled: [K][2][64][64]
    int last)
{
    __shared__ __align__(16) _Float16 Klds[2][2 * D * D];     // 2 x 16 KB double buffer

    const int b0   = blockIdx.x * 2;
    const int t    = threadIdx.x;
    const int wv   = t >> 6;
    const int lane = t & 63;
    const int l31  = lane & 31;
    const int hl   = lane >> 5;
    const int wr   = wv >> 1;
    const int wc   = wv & 1;

    // ---- hoisted A1: full rho^T for rho r=wc (rows 32*lh + l31) ----
    half8 a1re[2][4], a1im[2][4];
    {
        const _Float16* rb = rho_in + (size_t)(b0 + wc) * 2 * D * D;
        #pragma unroll
        for (int lh = 0; lh < 2; ++lh) {
            const int row = 32 * lh + l31;
            #pragma unroll
            for (int ks = 0; ks < 4; ++ks) {
                const int col = 16 * ks + 8 * hl;
                a1re[lh][ks] = *(const half8*)(rb + row * D + col);
                a1im[lh][ks] = *(const half8*)(rb + D * D + row * D + col);
            }
        }
    }

    // ---- preload K_0 into Klds[0] (async, drained by barrier) ----
    {
        const char* kb = (const char*)kraus;
        const int off = wv * 4096;
        #pragma unroll
        for (int rr = 0; rr < 4; ++rr)
            GLDS16(kb + off + rr * 1024 + lane * 16, (char*)&Klds[0][0] + off + rr * 1024);
    }

    f32x16 accRe[2], accIm[2];
    #pragma unroll
    for (int mt = 0; mt < 2; ++mt)
        #pragma unroll
        for (int i = 0; i < 16; ++i) { accRe[mt][i] = 0.f; accIm[mt][i] = 0.f; }

    __syncthreads();

    #pragma unroll 1
    for (int k = 0; k < NKR; ++k) {
        // async prefetch K_{k+1} into the other buffer; overlaps all compute this iter,
        // drained by the end-of-iter barrier's vmcnt(0).
        if (k + 1 < NKR) {
            const char* kb = (const char*)(kraus + (size_t)(k + 1) * 2 * D * D);
            const int off = wv * 4096;
            #pragma unroll
            for (int rr = 0; rr < 4; ++rr)
                GLDS16(kb + off + rr * 1024 + lane * 16,
                       (char*)&Klds[(k + 1) & 1][0] + off + rr * 1024);
        }
        const _Float16* KB = &Klds[0][0] + (k & 1) * (2 * D * D);
        if (wr == 0) kstep<0>(KB, a1re, a1im, accRe, accIm, l31, hl);
        else         kstep<1>(KB, a1re, a1im, accRe, accIm, l31, hl);
        __syncthreads();
    }

    // ---- epilogue: acc lane=col m_rel, reg 4g+j -> row i = 32wr + 8g + 4hl + j ----
    if (!last) {
        _Float16* ob = rho_out + (size_t)(b0 + wc) * 2 * D * D;
        #pragma unroll
        for (int mt = 0; mt < 2; ++mt) {
            const int m = 32 * mt + l31;
            #pragma unroll
            for (int g = 0; g < 4; ++g) {
                Pack4 pr, pi;
                #pragma unroll
                for (int j = 0; j < 4; ++j) {
                    pr.h[j] = (_Float16)accRe[mt][4 * g + j];
                    pi.h[j] = (_Float16)accIm[mt][4 * g + j];
                }
                const int i0 = 32 * wr + 8 * g + 4 * hl;
                *(uint2*)(ob + m * D + i0)         = pr.u;   // rho_new^T[m][i]
                *(uint2*)(ob + D * D + m * D + i0) = pi.u;
            }
        }
    } else {
        float* o0 = final_out + (size_t)(b0 + wc) * 4096;            // [0][b][i][m]
        float* o1 = final_out + (size_t)(NB + b0 + wc) * 4096;       // [1][b][i][m]
        #pragma unroll
        for (int mt = 0; mt < 2; ++mt) {
            const int m = 32 * mt + l31;
            #pragma unroll
            for (int g = 0; g < 4; ++g) {
                #pragma unroll
                for (int j = 0; j < 4; ++j) {
                    const int i = 32 * wr + 8 * g + 4 * hl + j;
                    o0[i * D + m] = accRe[mt][4 * g + j];
                    o1[i * D + m] = accIm[mt][4 * g + j];
                }
            }
        }
    }
}

extern "C" void kernel_launch(void* const* d_in, const int* in_sizes, int n_in,
                              void* d_out, int out_size, void* d_ws, size_t ws_size,
                              hipStream_t stream) {
    const float* state_re = (const float*)d_in[0];
    const float* state_im = (const float*)d_in[1];
    const float* kraus_re = (const float*)d_in[2];
    const float* kraus_im = (const float*)d_in[3];

    _Float16* kraus_h = (_Float16*)d_ws;                         // 2 MB in ws (swizzled)
    // ping-pong rho buffers live inside d_out (2 x 16 MB = out_size exactly).
    _Float16* bufA = (_Float16*)d_out;
    _Float16* bufB = (_Float16*)((char*)d_out + (size_t)NB * 2 * D * D * sizeof(_Float16));
    float* fout = (float*)d_out;

    kconv_kernel<<<dim3(512, 2), 256, 0, stream>>>(kraus_re, kraus_im, kraus_h);
    sconv_kernel<<<NB, 256, 0, stream>>>(state_re, state_im, bufA);

    for (int l = 0; l < NL; ++l) {
        const _Float16* in = (l & 1) ? bufB : bufA;
        _Float16* out      = (l & 1) ? bufA : bufB;
        layer_kernel<<<NB / 2, 256, 0, stream>>>(in, out, fout,
                                                 kraus_h + (size_t)l * NKR * 2 * D * D,
                                                 (l == NL - 1) ? 1 : 0);
    }
}